// Round 1
// baseline (3601.528 us; speedup 1.0000x reference)
//
#include <hip/hip_runtime.h>
#include <hip/hip_bf16.h>
#include <math.h>

#define H 1024
#define N1 2048
#define BATCH 8
#define SEQ 4096
#define M_TOT (BATCH*SEQ)
#define EPS 1e-5f
#define MIX 0.1f

#define BM 64
#define BN 64
#define BK 16

static __device__ __forceinline__ float bf16bits_to_f32(unsigned short u) {
    return __uint_as_float(((unsigned)u) << 16);
}

// ---------------- GEMM1: C1 = x @ W_to + b_to, epilogue: phase stats + bf16 store ----
__global__ __launch_bounds__(256) void gemm1_kernel(
    const float* __restrict__ x, const float* __restrict__ Wt,
    const float* __restrict__ bt, __hip_bfloat16* __restrict__ c1,
    float* __restrict__ sums)
{
    __shared__ float As[BK][BM];
    __shared__ float Br[BK][BN];
    __shared__ float Bi[BK][BN];
    __shared__ float red[4][16][4][2]; // wave, tx, j, {cos,sin}

    const int t  = threadIdx.x;
    const int m0 = blockIdx.y * BM;
    const int n0 = blockIdx.x * BN;   // pair-column tile: real col n, imag col n+H
    const int tx = t & 15, ty = t >> 4;

    float cr[4][4] = {}; float ci[4][4] = {};

    const int lm = t >> 2;          // 0..63  (A row)
    const int lk = (t & 3) * 4;     // 0,4,8,12
    const int bk_ = t >> 4;         // 0..15  (B k-row)
    const int bn_ = (t & 15) * 4;   // 0..60

    for (int k0 = 0; k0 < H; k0 += BK) {
        float4 av = *(const float4*)(x + (size_t)(m0 + lm) * H + k0 + lk);
        As[lk+0][lm] = av.x; As[lk+1][lm] = av.y; As[lk+2][lm] = av.z; As[lk+3][lm] = av.w;
        float4 bv = *(const float4*)(Wt + (size_t)(k0 + bk_) * N1 + n0 + bn_);
        *(float4*)&Br[bk_][bn_] = bv;
        float4 bw = *(const float4*)(Wt + (size_t)(k0 + bk_) * N1 + H + n0 + bn_);
        *(float4*)&Bi[bk_][bn_] = bw;
        __syncthreads();
        #pragma unroll
        for (int k = 0; k < BK; ++k) {
            float a[4], br[4], bi[4];
            #pragma unroll
            for (int i = 0; i < 4; ++i) a[i] = As[k][ty*4+i];
            #pragma unroll
            for (int j = 0; j < 4; ++j) { br[j] = Br[k][tx*4+j]; bi[j] = Bi[k][tx*4+j]; }
            #pragma unroll
            for (int i = 0; i < 4; ++i)
                #pragma unroll
                for (int j = 0; j < 4; ++j) {
                    cr[i][j] += a[i]*br[j];
                    ci[i][j] += a[i]*bi[j];
                }
        }
        __syncthreads();
    }

    // epilogue: bias, phase, local cos/sin sums, bf16 store
    float lc[4] = {0,0,0,0}, ls[4] = {0,0,0,0};
    #pragma unroll
    for (int j = 0; j < 4; ++j) {
        float btr = bt[n0 + tx*4 + j];
        float bti = bt[H + n0 + tx*4 + j];
        #pragma unroll
        for (int i = 0; i < 4; ++i) {
            float r  = cr[i][j] + btr;
            float im = ci[i][j] + bti;
            cr[i][j] = r; ci[i][j] = im;
            float ph = atan2f(im, r);
            lc[j] += cosf(ph);
            ls[j] += sinf(ph);
        }
    }
    #pragma unroll
    for (int i = 0; i < 4; ++i) {
        const size_t m = (size_t)(m0 + ty*4 + i);
        #pragma unroll
        for (int j = 0; j < 4; ++j) {
            const int n = n0 + tx*4 + j;
            c1[m*N1 + n]     = __float2bfloat16(cr[i][j]);
            c1[m*N1 + H + n] = __float2bfloat16(ci[i][j]);
        }
    }
    // reduce the 4 ty-values within each wave (lane = (ty&3)*16 + tx)
    #pragma unroll
    for (int j = 0; j < 4; ++j) {
        lc[j] += __shfl_down(lc[j], 32); lc[j] += __shfl_down(lc[j], 16);
        ls[j] += __shfl_down(ls[j], 32); ls[j] += __shfl_down(ls[j], 16);
    }
    const int wv = t >> 6, lane = t & 63;
    if (lane < 16) {
        #pragma unroll
        for (int j = 0; j < 4; ++j) {
            red[wv][lane][j][0] = lc[j];
            red[wv][lane][j][1] = ls[j];
        }
    }
    __syncthreads();
    if (t < 128) {
        const int which = t & 1, j = (t >> 1) & 3, txx = t >> 3;
        float s = red[0][txx][j][which] + red[1][txx][j][which]
                + red[2][txx][j][which] + red[3][txx][j][which];
        const int b = m0 >> 12;            // SEQ = 4096 rows per batch
        const int h = n0 + txx*4 + j;
        atomicAdd(&sums[(b*2 + which)*H + h], s);
    }
}

// ---------------- elementwise phase mixing (in-place on bf16 C1) ----------------
__global__ __launch_bounds__(256) void phase_mix_kernel(
    __hip_bfloat16* __restrict__ c1, const float* __restrict__ sums,
    const float* __restrict__ ps)
{
    size_t idx = (size_t)blockIdx.x * blockDim.x + threadIdx.x;
    if (idx >= (size_t)M_TOT * H) return;
    const int h = (int)(idx & (H - 1));
    const size_t m = idx >> 10;
    const int b = (int)(m >> 12);

    float r  = bf16bits_to_f32(((const unsigned short*)c1)[m*N1 + h]);
    float im = bf16bits_to_f32(((const unsigned short*)c1)[m*N1 + H + h]);
    float mag = sqrtf(r*r + im*im + EPS);
    float ph  = atan2f(im, r);
    float mc = sums[(b*2 + 0)*H + h] * (1.0f / SEQ);
    float ms = sums[(b*2 + 1)*H + h] * (1.0f / SEQ);
    float sh = ph + ps[h];
    float mixed = cosf(sh)*mc + sinf(sh)*ms;
    float np = ph + MIX * mixed;
    c1[m*N1 + h]     = __float2bfloat16(mag * cosf(np));
    c1[m*N1 + H + h] = __float2bfloat16(mag * sinf(np));
}

// ---------------- GEMM2: out = C1' @ W_from + b_from ----------------
__global__ __launch_bounds__(256) void gemm2_kernel(
    const __hip_bfloat16* __restrict__ a, const float* __restrict__ Wf,
    const float* __restrict__ bf, float* __restrict__ out)
{
    __shared__ float As[BK][BM];
    __shared__ float Bs[BK][BN];

    const int t  = threadIdx.x;
    const int m0 = blockIdx.y * BM;
    const int n0 = blockIdx.x * BN;
    const int tx = t & 15, ty = t >> 4;

    float acc[4][4] = {};

    const int lm = t >> 2;
    const int lk = (t & 3) * 4;
    const int bk_ = t >> 4;
    const int bn_ = (t & 15) * 4;

    const unsigned short* au = (const unsigned short*)a;

    for (int k0 = 0; k0 < N1; k0 += BK) {
        ushort4 av = *(const ushort4*)(au + (size_t)(m0 + lm) * N1 + k0 + lk);
        As[lk+0][lm] = bf16bits_to_f32(av.x);
        As[lk+1][lm] = bf16bits_to_f32(av.y);
        As[lk+2][lm] = bf16bits_to_f32(av.z);
        As[lk+3][lm] = bf16bits_to_f32(av.w);
        float4 bv = *(const float4*)(Wf + (size_t)(k0 + bk_) * H + n0 + bn_);
        *(float4*)&Bs[bk_][bn_] = bv;
        __syncthreads();
        #pragma unroll
        for (int k = 0; k < BK; ++k) {
            float av2[4], bv2[4];
            #pragma unroll
            for (int i = 0; i < 4; ++i) av2[i] = As[k][ty*4+i];
            #pragma unroll
            for (int j = 0; j < 4; ++j) bv2[j] = Bs[k][tx*4+j];
            #pragma unroll
            for (int i = 0; i < 4; ++i)
                #pragma unroll
                for (int j = 0; j < 4; ++j)
                    acc[i][j] += av2[i]*bv2[j];
        }
        __syncthreads();
    }
    #pragma unroll
    for (int i = 0; i < 4; ++i) {
        const size_t m = (size_t)(m0 + ty*4 + i);
        #pragma unroll
        for (int j = 0; j < 4; ++j) {
            const int n = n0 + tx*4 + j;
            out[m*H + n] = acc[i][j] + bf[n];
        }
    }
}

extern "C" void kernel_launch(void* const* d_in, const int* in_sizes, int n_in,
                              void* d_out, int out_size, void* d_ws, size_t ws_size,
                              hipStream_t stream) {
    const float* x  = (const float*)d_in[0];
    const float* Wt = (const float*)d_in[1];
    const float* bt = (const float*)d_in[2];
    const float* Wf = (const float*)d_in[3];
    const float* bf = (const float*)d_in[4];
    const float* ps = (const float*)d_in[5];
    float* out = (float*)d_out;

    const size_t c1_bytes   = (size_t)M_TOT * N1 * sizeof(__hip_bfloat16); // 128 MiB
    const size_t sums_bytes = (size_t)BATCH * 2 * H * sizeof(float);       // 64 KiB
    if (ws_size < c1_bytes + sums_bytes) return;  // visible-fail guard (output stays zero)

    __hip_bfloat16* c1 = (__hip_bfloat16*)d_ws;
    float* sums = (float*)((char*)d_ws + c1_bytes);

    hipMemsetAsync(sums, 0, sums_bytes, stream);

    dim3 blk(256);
    dim3 g1(H / BN, M_TOT / BM);     // 16 x 512
    gemm1_kernel<<<g1, blk, 0, stream>>>(x, Wt, bt, c1, sums);

    size_t total = (size_t)M_TOT * H;
    phase_mix_kernel<<<dim3((unsigned)((total + 255) / 256)), blk, 0, stream>>>(c1, sums, ps);

    dim3 g2(H / BN, M_TOT / BM);     // 16 x 512
    gemm2_kernel<<<g2, blk, 0, stream>>>(c1, Wf, bf, out);
}

// Round 2
// 545.698 us; speedup vs baseline: 6.5999x; 6.5999x over previous
//
#include <hip/hip_runtime.h>
#include <hip/hip_bf16.h>
#include <math.h>

#define H 1024
#define N1 2048
#define BATCH 8
#define SEQ 4096
#define M_TOT (BATCH*SEQ)
#define EPS 1e-5f
#define MIX 0.1f

typedef __attribute__((ext_vector_type(8))) short bf16x8;
typedef __attribute__((ext_vector_type(4))) float f32x4;
typedef unsigned short ushort_t;
typedef unsigned int uint_t;

static __device__ __forceinline__ float bf2f(unsigned short u) {
    return __uint_as_float(((unsigned)u) << 16);
}
static __device__ __forceinline__ unsigned short f2bf(float x) {
    __hip_bfloat16 h = __float2bfloat16(x);
    return *reinterpret_cast<unsigned short*>(&h);
}
static __device__ __forceinline__ void gload16(const void* g, void* l) {
    __builtin_amdgcn_global_load_lds(
        (const __attribute__((address_space(1))) unsigned int*)g,
        (__attribute__((address_space(3))) unsigned int*)l,
        16, 0, 0);
}

// ---------- f32 -> bf16 bulk convert (8 elems/thread) ----------
__global__ __launch_bounds__(256) void cvt_f32_bf16(
    const float* __restrict__ in, unsigned short* __restrict__ out, size_t n)
{
    size_t i = ((size_t)blockIdx.x * 256 + threadIdx.x) * 8;
    if (i >= n) return;
    float4 a = *(const float4*)(in + i);
    float4 b = *(const float4*)(in + i + 4);
    union { unsigned short u[8]; uint4 v; } p;
    p.u[0] = f2bf(a.x); p.u[1] = f2bf(a.y); p.u[2] = f2bf(a.z); p.u[3] = f2bf(a.w);
    p.u[4] = f2bf(b.x); p.u[5] = f2bf(b.y); p.u[6] = f2bf(b.z); p.u[7] = f2bf(b.w);
    *(uint4*)(out + i) = p.v;
}

// ---------- f32 [R][C] -> bf16 [C][R] transpose+convert ----------
__global__ __launch_bounds__(256) void transpose_cvt(
    const float* __restrict__ in, unsigned short* __restrict__ out, int R, int C)
{
    __shared__ float tile[64][65];
    const int c0 = blockIdx.x * 64, r0 = blockIdx.y * 64;
    const int tc = threadIdx.x & 63, tr4 = (threadIdx.x >> 6) * 16;
    #pragma unroll
    for (int rr = 0; rr < 16; ++rr)
        tile[tr4 + rr][tc] = in[(size_t)(r0 + tr4 + rr) * C + c0 + tc];
    __syncthreads();
    #pragma unroll
    for (int rr = 0; rr < 16; ++rr)
        out[(size_t)(c0 + tr4 + rr) * R + r0 + tc] = f2bf(tile[tc][tr4 + rr]);
}

// ---------- MFMA GEMM: C[M][N] = A[M][K] * Bt[N][K]^T + bias ----------
// m97 structure: 128x128 tile, BK=32, 4 waves (2x2), 16x16x32 MFMA, global_load_lds
template<int KDIM, bool BF16_OUT>
__global__ __launch_bounds__(256) void mfma_gemm(
    const unsigned short* __restrict__ A,
    const unsigned short* __restrict__ Bt,
    const float* __restrict__ bias,
    void* __restrict__ Cout, int NTOT)
{
    __shared__ unsigned short As[128 * 32];
    __shared__ unsigned short Bs[128 * 32];

    const int t    = threadIdx.x;
    const int lane = t & 63;
    const int wid  = t >> 6;
    const int wr   = wid >> 1, wc = wid & 1;
    const int m0   = blockIdx.y * 128;
    const int n0   = blockIdx.x * 128;

    f32x4 acc[4][4] = {};

    // staging: each thread two 16B chunks per operand
    const int sr = t >> 2;            // 0..63 row-in-chunk
    const int sc = (t & 3) * 8;       // k element offset
    const unsigned short* Ag0 = A  + (size_t)(m0 + sr)      * KDIM + sc;
    const unsigned short* Ag1 = A  + (size_t)(m0 + 64 + sr) * KDIM + sc;
    const unsigned short* Bg0 = Bt + (size_t)(n0 + sr)      * KDIM + sc;
    const unsigned short* Bg1 = Bt + (size_t)(n0 + 64 + sr) * KDIM + sc;
    unsigned short* Al0 = &As[t * 8];
    unsigned short* Al1 = &As[2048 + t * 8];
    unsigned short* Bl0 = &Bs[t * 8];
    unsigned short* Bl1 = &Bs[2048 + t * 8];

    const int fr = lane & 15;         // fragment row/col within 16
    const int kb = (lane >> 4) * 8;   // k sub-block (elements)

    for (int k0 = 0; k0 < KDIM; k0 += 32) {
        gload16(Ag0 + k0, Al0);
        gload16(Ag1 + k0, Al1);
        gload16(Bg0 + k0, Bl0);
        gload16(Bg1 + k0, Bl1);
        __syncthreads();   // drains vmcnt(0): LDS tiles ready

        bf16x8 af[4], bfv[4];
        #pragma unroll
        for (int i = 0; i < 4; ++i)
            af[i] = *(const bf16x8*)&As[(wr * 64 + i * 16 + fr) * 32 + kb];
        #pragma unroll
        for (int j = 0; j < 4; ++j)
            bfv[j] = *(const bf16x8*)&Bs[(wc * 64 + j * 16 + fr) * 32 + kb];

        #pragma unroll
        for (int i = 0; i < 4; ++i)
            #pragma unroll
            for (int j = 0; j < 4; ++j)
                acc[i][j] = __builtin_amdgcn_mfma_f32_16x16x32_bf16(
                    af[i], bfv[j], acc[i][j], 0, 0, 0);
        __syncthreads();   // protect LDS before next-iter overwrite
    }

    // epilogue: C/D layout col=lane&15, row=(lane>>4)*4+r  [m89-verified]
    const int rbase = (lane >> 4) * 4;
    #pragma unroll
    for (int i = 0; i < 4; ++i) {
        #pragma unroll
        for (int j = 0; j < 4; ++j) {
            const int col = n0 + wc * 64 + j * 16 + fr;
            const float bb = bias[col];
            #pragma unroll
            for (int r = 0; r < 4; ++r) {
                const size_t row = (size_t)(m0 + wr * 64 + i * 16 + rbase + r);
                const float v = acc[i][j][r] + bb;
                if (BF16_OUT)
                    ((unsigned short*)Cout)[row * NTOT + col] = f2bf(v);
                else
                    ((float*)Cout)[row * NTOT + col] = v;
            }
        }
    }
}

// ---------- per-(b,h) sums of cos/sin(phase) — no trig: cos=r/|z|, sin=i/|z| ----------
__global__ __launch_bounds__(256) void stats_kernel(
    const unsigned short* __restrict__ c1, float* __restrict__ sums)
{
    const int t  = threadIdx.x;
    const int h0 = blockIdx.x * 512 + t * 2;
    const int b  = blockIdx.y;
    const int s0 = blockIdx.z * 256;
    const uint_t* cu = (const uint_t*)c1;
    const size_t base = ((size_t)b * SEQ + s0) * 1024;  // uint row stride 1024
    float lc0 = 0, ls0 = 0, lc1 = 0, ls1 = 0;
    for (int s = 0; s < 256; ++s) {
        uint_t rv = cu[base + (size_t)s * 1024 + (h0 >> 1)];
        uint_t iv = cu[base + (size_t)s * 1024 + 512 + (h0 >> 1)];
        float r0 = bf2f(rv & 0xffff), r1 = bf2f(rv >> 16);
        float i0 = bf2f(iv & 0xffff), i1 = bf2f(iv >> 16);
        float n0 = rsqrtf(fmaxf(r0 * r0 + i0 * i0, 1e-30f));
        float n1 = rsqrtf(fmaxf(r1 * r1 + i1 * i1, 1e-30f));
        lc0 += r0 * n0; ls0 += i0 * n0;
        lc1 += r1 * n1; ls1 += i1 * n1;
    }
    atomicAdd(&sums[(b * 2 + 0) * H + h0],     lc0);
    atomicAdd(&sums[(b * 2 + 1) * H + h0],     ls0);
    atomicAdd(&sums[(b * 2 + 0) * H + h0 + 1], lc1);
    atomicAdd(&sums[(b * 2 + 1) * H + h0 + 1], ls1);
}

// ---------- fold phase_shifts + means into P,Q per (b,h) ----------
__global__ void finalize_pq(const float* __restrict__ sums, const float* __restrict__ ps,
                            float* __restrict__ P, float* __restrict__ Q)
{
    int i = blockIdx.x * 256 + threadIdx.x;   // 8192
    int b = i >> 10, h = i & (H - 1);
    float mc = sums[(b * 2 + 0) * H + h] * (1.0f / SEQ);
    float ms = sums[(b * 2 + 1) * H + h] * (1.0f / SEQ);
    float cp = cosf(ps[h]), sp = sinf(ps[h]);
    P[i] = mc * cp + ms * sp;
    Q[i] = ms * cp - mc * sp;
}

// ---------- phase mix, in place on bf16 c1, no transcendentals ----------
__global__ __launch_bounds__(256) void phase_mix(
    unsigned short* __restrict__ c1, const float* __restrict__ P,
    const float* __restrict__ Q)
{
    const size_t q = (size_t)blockIdx.x * 256 + threadIdx.x; // quad id
    const size_t m = q >> 8;
    const int hq = (int)(q & 255) * 4;
    const int b = (int)(m >> 12);
    uint2* cu = (uint2*)c1;
    const size_t ridx = ((size_t)m * N1 + hq) >> 2;
    const size_t iidx = ((size_t)m * N1 + H + hq) >> 2;
    uint2 rv = cu[ridx], iv = cu[iidx];
    float4 Pv = *(const float4*)&P[b * H + hq];
    float4 Qv = *(const float4*)&Q[b * H + hq];
    float r[4] = { bf2f(rv.x & 0xffff), bf2f(rv.x >> 16), bf2f(rv.y & 0xffff), bf2f(rv.y >> 16) };
    float im[4] = { bf2f(iv.x & 0xffff), bf2f(iv.x >> 16), bf2f(iv.y & 0xffff), bf2f(iv.y >> 16) };
    const float Pk[4] = { Pv.x, Pv.y, Pv.z, Pv.w };
    const float Qk[4] = { Qv.x, Qv.y, Qv.z, Qv.w };
    unsigned short outr[4], outi[4];
    #pragma unroll
    for (int e = 0; e < 4; ++e) {
        float tt = r[e] * r[e] + im[e] * im[e];
        float minv = rsqrtf(fmaxf(tt, 1e-30f));
        float d = MIX * (r[e] * Pk[e] + im[e] * Qk[e]) * minv;  // |d| <= ~0.1
        float d2 = d * d;
        float cd = 1.0f - d2 * (0.5f - d2 * (1.0f / 24.0f));
        float sd = d * (1.0f - d2 * ((1.0f / 6.0f) - d2 * (1.0f / 120.0f)));
        float sc = sqrtf(tt + EPS) * minv;  // mag/|z|
        outr[e] = f2bf(sc * (r[e] * cd - im[e] * sd));
        outi[e] = f2bf(sc * (im[e] * cd + r[e] * sd));
    }
    uint2 ro, io;
    ro.x = (uint_t)outr[0] | ((uint_t)outr[1] << 16);
    ro.y = (uint_t)outr[2] | ((uint_t)outr[3] << 16);
    io.x = (uint_t)outi[0] | ((uint_t)outi[1] << 16);
    io.y = (uint_t)outi[2] | ((uint_t)outi[3] << 16);
    cu[ridx] = ro;
    cu[iidx] = io;
}

extern "C" void kernel_launch(void* const* d_in, const int* in_sizes, int n_in,
                              void* d_out, int out_size, void* d_ws, size_t ws_size,
                              hipStream_t stream) {
    const float* x  = (const float*)d_in[0];
    const float* Wt = (const float*)d_in[1];
    const float* bt = (const float*)d_in[2];
    const float* Wf = (const float*)d_in[3];
    const float* bf = (const float*)d_in[4];
    const float* ps = (const float*)d_in[5];
    float* out = (float*)d_out;

    // ws layout: c1 (128Mi) | Wf_t (4Mi) | sums (64Ki) | P (32Ki) | Q (32Ki)
    const size_t c1_bytes  = (size_t)M_TOT * N1 * 2;       // 134217728
    const size_t wft_bytes = (size_t)H * N1 * 2;           // 4 Mi
    const size_t sums_bytes = (size_t)BATCH * 2 * H * 4;   // 64 Ki
    const size_t pq_bytes  = (size_t)BATCH * H * 4;        // 32 Ki each
    if (ws_size < c1_bytes + wft_bytes + sums_bytes + 2 * pq_bytes) return;

    unsigned short* c1  = (unsigned short*)d_ws;
    unsigned short* WfT = (unsigned short*)((char*)d_ws + c1_bytes);
    float* sums = (float*)((char*)d_ws + c1_bytes + wft_bytes);
    float* Pb   = (float*)((char*)d_ws + c1_bytes + wft_bytes + sums_bytes);
    float* Qb   = (float*)((char*)d_ws + c1_bytes + wft_bytes + sums_bytes + pq_bytes);

    // d_out doubles as scratch (fully overwritten by gemm2 at the end):
    //   [0, 64Mi): x_bf16   [64Mi, 68Mi): Wt_t
    unsigned short* xb  = (unsigned short*)d_out;
    unsigned short* WtT = (unsigned short*)d_out + (size_t)M_TOT * H;

    hipMemsetAsync(sums, 0, sums_bytes, stream);

    // 1. conversions
    cvt_f32_bf16<<<dim3((unsigned)(((size_t)M_TOT * H / 8 + 255) / 256)), 256, 0, stream>>>(
        x, xb, (size_t)M_TOT * H);
    transpose_cvt<<<dim3(N1 / 64, H / 64), 256, 0, stream>>>(Wt, WtT, H, N1);   // [H][2H] -> [2H][H]
    transpose_cvt<<<dim3(H / 64, N1 / 64), 256, 0, stream>>>(Wf, WfT, N1, H);   // [2H][H] -> [H][2H]

    // 2. GEMM1: c1 = x @ W_to + b_to   (M=32768, N=2048, K=1024), bf16 out
    mfma_gemm<H, true><<<dim3(N1 / 128, M_TOT / 128), 256, 0, stream>>>(
        xb, WtT, bt, (void*)c1, N1);

    // 3. phase stats  4. fold shifts  5. mix in place
    stats_kernel<<<dim3(2, BATCH, 16), 256, 0, stream>>>(c1, sums);
    finalize_pq<<<dim3(BATCH * H / 256), 256, 0, stream>>>(sums, ps, Pb, Qb);
    phase_mix<<<dim3((unsigned)((size_t)M_TOT * N1 / 4 / 256)), 256, 0, stream>>>(c1, Pb, Qb);

    // 6. GEMM2: out = c1 @ W_from + b_from  (M=32768, N=1024, K=2048), f32 out
    mfma_gemm<N1, false><<<dim3(H / 128, M_TOT / 128), 256, 0, stream>>>(
        c1, WfT, bf, (void*)out, H);
}

// Round 3
// 438.444 us; speedup vs baseline: 8.2143x; 1.2446x over previous
//
#include <hip/hip_runtime.h>
#include <hip/hip_bf16.h>
#include <math.h>

#define H 1024
#define N1 2048
#define BATCH 8
#define SEQ 4096
#define M_TOT (BATCH*SEQ)
#define EPS 1e-5f
#define MIX 0.1f

typedef __attribute__((ext_vector_type(8))) short bf16x8;
typedef __attribute__((ext_vector_type(4))) float f32x4;
typedef unsigned short ushort_t;
typedef unsigned int uint_t;

static __device__ __forceinline__ float bf2f(unsigned short u) {
    return __uint_as_float(((unsigned)u) << 16);
}
static __device__ __forceinline__ unsigned short f2bf(float x) {
    __hip_bfloat16 h = __float2bfloat16(x);
    return *reinterpret_cast<unsigned short*>(&h);
}
static __device__ __forceinline__ void gload16(const void* g, void* l) {
    __builtin_amdgcn_global_load_lds(
        (const __attribute__((address_space(1))) unsigned int*)g,
        (__attribute__((address_space(3))) unsigned int*)l,
        16, 0, 0);
}
// interleave perms: c in [0,2048)
static __device__ __forceinline__ int perm2h(int c)  { return ((c & 1023) << 1) | (c >> 10); }
static __device__ __forceinline__ int invperm(int k) { return (k >> 1) | ((k & 1) << 10); }

// ---------- f32 -> bf16 bulk convert (8 elems/thread) ----------
__global__ __launch_bounds__(256) void cvt_f32_bf16(
    const float* __restrict__ in, unsigned short* __restrict__ out, size_t n)
{
    size_t i = ((size_t)blockIdx.x * 256 + threadIdx.x) * 8;
    if (i >= n) return;
    float4 a = *(const float4*)(in + i);
    float4 b = *(const float4*)(in + i + 4);
    union { unsigned short u[8]; uint4 v; } p;
    p.u[0] = f2bf(a.x); p.u[1] = f2bf(a.y); p.u[2] = f2bf(a.z); p.u[3] = f2bf(a.w);
    p.u[4] = f2bf(b.x); p.u[5] = f2bf(b.y); p.u[6] = f2bf(b.z); p.u[7] = f2bf(b.w);
    *(uint4*)(out + i) = p.v;
}

// ---------- WtT: out[perm2h(c)][r] = Wt[r][c];  [1024][2048]f32 -> [2048][1024]bf16 ----------
__global__ __launch_bounds__(256) void transpose_wt(
    const float* __restrict__ in, unsigned short* __restrict__ out)
{
    __shared__ float tile[64][65];
    const int c0 = blockIdx.x * 64, r0 = blockIdx.y * 64;
    const int tc = threadIdx.x & 63, tr4 = (threadIdx.x >> 6) * 16;
    #pragma unroll
    for (int rr = 0; rr < 16; ++rr)
        tile[tr4 + rr][tc] = in[(size_t)(r0 + tr4 + rr) * N1 + c0 + tc];
    __syncthreads();
    #pragma unroll
    for (int rr = 0; rr < 16; ++rr)
        out[(size_t)perm2h(c0 + tr4 + rr) * H + r0 + tc] = f2bf(tile[tc][tr4 + rr]);
}

// ---------- WfT: out[n][k] = Wf[invperm(k)][n];  [2048][1024]f32 -> [1024][2048]bf16 ----------
__global__ __launch_bounds__(256) void transpose_wf(
    const float* __restrict__ in, unsigned short* __restrict__ out)
{
    __shared__ float tile[64][65];
    const int n0 = blockIdx.x * 64, k0 = blockIdx.y * 64;
    const int tc = threadIdx.x & 63, tr4 = (threadIdx.x >> 6) * 16;
    #pragma unroll
    for (int rr = 0; rr < 16; ++rr)
        tile[tr4 + rr][tc] = in[(size_t)invperm(k0 + tr4 + rr) * H + n0 + tc];
    __syncthreads();
    #pragma unroll
    for (int rr = 0; rr < 16; ++rr)
        out[(size_t)(n0 + tr4 + rr) * N1 + k0 + tc] = f2bf(tile[tc][tr4 + rr]);
}

// ---------- shared MFMA core: 128x128 tile, BK=32, 4 waves, 16x16x32 bf16 ----------
template<int KDIM>
static __device__ __forceinline__ void gemm_core(
    const unsigned short* __restrict__ A, const unsigned short* __restrict__ Bt,
    int m0, int n0, int t, unsigned short* As, unsigned short* Bs,
    f32x4 (&acc)[4][4])
{
    const int lane = t & 63;
    const int wid  = t >> 6;
    const int wr   = wid >> 1, wc = wid & 1;

    const int sr = t >> 2;
    const int sc = (t & 3) * 8;
    const unsigned short* Ag0 = A  + (size_t)(m0 + sr)      * KDIM + sc;
    const unsigned short* Ag1 = A  + (size_t)(m0 + 64 + sr) * KDIM + sc;
    const unsigned short* Bg0 = Bt + (size_t)(n0 + sr)      * KDIM + sc;
    const unsigned short* Bg1 = Bt + (size_t)(n0 + 64 + sr) * KDIM + sc;
    unsigned short* Al0 = &As[t * 8];
    unsigned short* Al1 = &As[2048 + t * 8];
    unsigned short* Bl0 = &Bs[t * 8];
    unsigned short* Bl1 = &Bs[2048 + t * 8];

    const int fr = lane & 15;
    const int kb = (lane >> 4) * 8;

    for (int k0 = 0; k0 < KDIM; k0 += 32) {
        gload16(Ag0 + k0, Al0);
        gload16(Ag1 + k0, Al1);
        gload16(Bg0 + k0, Bl0);
        gload16(Bg1 + k0, Bl1);
        __syncthreads();

        bf16x8 af[4], bfv[4];
        #pragma unroll
        for (int i = 0; i < 4; ++i)
            af[i] = *(const bf16x8*)&As[(wr * 64 + i * 16 + fr) * 32 + kb];
        #pragma unroll
        for (int j = 0; j < 4; ++j)
            bfv[j] = *(const bf16x8*)&Bs[(wc * 64 + j * 16 + fr) * 32 + kb];

        #pragma unroll
        for (int i = 0; i < 4; ++i)
            #pragma unroll
            for (int j = 0; j < 4; ++j)
                acc[i][j] = __builtin_amdgcn_mfma_f32_16x16x32_bf16(
                    af[i], bfv[j], acc[i][j], 0, 0, 0);
        __syncthreads();
    }
}

// ---------- GEMM1 + bias + fused phase stats, interleaved bf16 out ----------
__global__ __launch_bounds__(256) void gemm1_mfma(
    const unsigned short* __restrict__ A, const unsigned short* __restrict__ Bt,
    const float* __restrict__ bt, unsigned short* __restrict__ c1,
    float* __restrict__ sums)
{
    __shared__ unsigned short As[128 * 32];
    __shared__ unsigned short Bs[128 * 32];

    const int t = threadIdx.x;
    // XCD-chunked swizzle: nwg=4096, 512 per XCD
    const unsigned wg = ((blockIdx.x & 7) << 9) | (blockIdx.x >> 3);
    const int n0 = (wg & 15) * 128;
    const int m0 = (wg >> 4) * 128;

    f32x4 acc[4][4] = {};
    gemm_core<H>(A, Bt, m0, n0, t, As, Bs, acc);

    const int lane = t & 63;
    const int wid  = t >> 6;
    const int wr   = wid >> 1, wc = wid & 1;
    const int fr   = lane & 15;
    const int rbase = (lane >> 4) * 4;

    // bias (interleaved col -> original bt index)
    #pragma unroll
    for (int j = 0; j < 4; ++j) {
        const int n = n0 + wc * 64 + j * 16 + fr;
        const float bb = bt[invperm(n)];
        #pragma unroll
        for (int i = 0; i < 4; ++i)
            #pragma unroll
            for (int r = 0; r < 4; ++r)
                acc[i][j][r] += bb;
    }

    // c1 write (bf16, interleaved layout)
    #pragma unroll
    for (int i = 0; i < 4; ++i)
        #pragma unroll
        for (int j = 0; j < 4; ++j) {
            const int col = n0 + wc * 64 + j * 16 + fr;
            #pragma unroll
            for (int r = 0; r < 4; ++r) {
                const size_t row = (size_t)(m0 + wr * 64 + i * 16 + rbase + r);
                c1[row * N1 + col] = f2bf(acc[i][j][r]);
            }
        }

    // fused stats: cos=r/|z|, sin=i/|z|; even-fr lane holds real, odd holds imag
    float lc[4] = {0, 0, 0, 0}, ls[4] = {0, 0, 0, 0};
    #pragma unroll
    for (int j = 0; j < 4; ++j)
        #pragma unroll
        for (int i = 0; i < 4; ++i)
            #pragma unroll
            for (int r = 0; r < 4; ++r) {
                const float own = acc[i][j][r];
                const float oth = __shfl_xor(own, 1);
                const float re = (fr & 1) ? oth : own;
                const float im = (fr & 1) ? own : oth;
                const float rsq = rsqrtf(fmaxf(re * re + im * im, 1e-30f));
                lc[j] += re * rsq;
                ls[j] += im * rsq;
            }
    #pragma unroll
    for (int j = 0; j < 4; ++j) {
        lc[j] += __shfl_xor(lc[j], 16); lc[j] += __shfl_xor(lc[j], 32);
        ls[j] += __shfl_xor(ls[j], 16); ls[j] += __shfl_xor(ls[j], 32);
    }
    if (lane < 16 && !(lane & 1)) {   // g==0, even fr: unique (h) owners
        const int b = m0 >> 12;
        #pragma unroll
        for (int j = 0; j < 4; ++j) {
            const int h = (n0 + wc * 64 + j * 16 + fr) >> 1;
            atomicAdd(&sums[(b * 2 + 0) * H + h], lc[j]);
            atomicAdd(&sums[(b * 2 + 1) * H + h], ls[j]);
        }
    }
}

// ---------- GEMM2: out = c1 @ WfT^T + bf, f32 out ----------
__global__ __launch_bounds__(256) void gemm2_mfma(
    const unsigned short* __restrict__ A, const unsigned short* __restrict__ Bt,
    const float* __restrict__ bf, float* __restrict__ out)
{
    __shared__ unsigned short As[128 * 32];
    __shared__ unsigned short Bs[128 * 32];

    const int t = threadIdx.x;
    // XCD-chunked swizzle: nwg=2048, 256 per XCD
    const unsigned wg = ((blockIdx.x & 7) << 8) | (blockIdx.x >> 3);
    const int n0 = (wg & 7) * 128;
    const int m0 = (wg >> 3) * 128;

    f32x4 acc[4][4] = {};
    gemm_core<N1>(A, Bt, m0, n0, t, As, Bs, acc);

    const int lane = t & 63;
    const int wid  = t >> 6;
    const int wr   = wid >> 1, wc = wid & 1;
    const int fr   = lane & 15;
    const int rbase = (lane >> 4) * 4;

    #pragma unroll
    for (int i = 0; i < 4; ++i)
        #pragma unroll
        for (int j = 0; j < 4; ++j) {
            const int col = n0 + wc * 64 + j * 16 + fr;
            const float bb = bf[col];
            #pragma unroll
            for (int r = 0; r < 4; ++r) {
                const size_t row = (size_t)(m0 + wr * 64 + i * 16 + rbase + r);
                out[row * H + col] = acc[i][j][r] + bb;
            }
        }
}

// ---------- fold phase_shifts + means into P,Q per (b,h) ----------
__global__ void finalize_pq(const float* __restrict__ sums, const float* __restrict__ ps,
                            float* __restrict__ P, float* __restrict__ Q)
{
    int i = blockIdx.x * 256 + threadIdx.x;   // 8192
    int b = i >> 10, h = i & (H - 1);
    float mc = sums[(b * 2 + 0) * H + h] * (1.0f / SEQ);
    float ms = sums[(b * 2 + 1) * H + h] * (1.0f / SEQ);
    float cp = cosf(ps[h]), sp = sinf(ps[h]);
    P[i] = mc * cp + ms * sp;
    Q[i] = ms * cp - mc * sp;
}

// ---------- phase mix, in place, interleaved pairs, 4 pairs/thread ----------
__global__ __launch_bounds__(256) void phase_mix(
    unsigned short* __restrict__ c1, const float* __restrict__ P,
    const float* __restrict__ Q)
{
    const size_t total = (size_t)M_TOT * N1 / 8;
    for (size_t q = (size_t)blockIdx.x * 256 + threadIdx.x; q < total;
         q += (size_t)gridDim.x * 256) {
        const size_t m = q >> 8;               // 256 8-short chunks per row
        const int off = ((int)q & 255) * 8;    // short offset in row
        const int b = (int)(m >> 12);
        const int h0 = off >> 1;
        uint4* cu = (uint4*)c1;
        const size_t idx = ((size_t)m * N1 + off) >> 3;
        uint4 v = cu[idx];
        float4 Pv = *(const float4*)&P[b * H + h0];
        float4 Qv = *(const float4*)&Q[b * H + h0];
        const uint_t w[4] = { v.x, v.y, v.z, v.w };
        const float Pk[4] = { Pv.x, Pv.y, Pv.z, Pv.w };
        const float Qk[4] = { Qv.x, Qv.y, Qv.z, Qv.w };
        uint_t o[4];
        #pragma unroll
        for (int e = 0; e < 4; ++e) {
            float r  = bf2f(w[e] & 0xffff);
            float im = bf2f(w[e] >> 16);
            float tt = r * r + im * im;
            float minv = rsqrtf(fmaxf(tt, 1e-30f));
            float d = MIX * (r * Pk[e] + im * Qk[e]) * minv;   // |d| <= ~0.1
            float d2 = d * d;
            float cd = 1.0f - d2 * (0.5f - d2 * (1.0f / 24.0f));
            float sd = d * (1.0f - d2 * ((1.0f / 6.0f) - d2 * (1.0f / 120.0f)));
            float sc = sqrtf(tt + EPS) * minv;                  // mag/|z|
            o[e] = (uint_t)f2bf(sc * (r * cd - im * sd))
                 | ((uint_t)f2bf(sc * (im * cd + r * sd)) << 16);
        }
        v.x = o[0]; v.y = o[1]; v.z = o[2]; v.w = o[3];
        cu[idx] = v;
    }
}

extern "C" void kernel_launch(void* const* d_in, const int* in_sizes, int n_in,
                              void* d_out, int out_size, void* d_ws, size_t ws_size,
                              hipStream_t stream) {
    const float* x  = (const float*)d_in[0];
    const float* Wt = (const float*)d_in[1];
    const float* bt = (const float*)d_in[2];
    const float* Wf = (const float*)d_in[3];
    const float* bf = (const float*)d_in[4];
    const float* ps = (const float*)d_in[5];
    float* out = (float*)d_out;

    // ws: c1 (128Mi) | WfT (4Mi) | sums (64Ki) | P (32Ki) | Q (32Ki)
    const size_t c1_bytes   = (size_t)M_TOT * N1 * 2;
    const size_t wft_bytes  = (size_t)H * N1 * 2;
    const size_t sums_bytes = (size_t)BATCH * 2 * H * 4;
    const size_t pq_bytes   = (size_t)BATCH * H * 4;
    if (ws_size < c1_bytes + wft_bytes + sums_bytes + 2 * pq_bytes) return;

    unsigned short* c1  = (unsigned short*)d_ws;
    unsigned short* WfT = (unsigned short*)((char*)d_ws + c1_bytes);
    float* sums = (float*)((char*)d_ws + c1_bytes + wft_bytes);
    float* Pb   = (float*)((char*)d_ws + c1_bytes + wft_bytes + sums_bytes);
    float* Qb   = (float*)((char*)d_ws + c1_bytes + wft_bytes + sums_bytes + pq_bytes);

    // d_out doubles as scratch until gemm2 overwrites it:
    unsigned short* xb  = (unsigned short*)d_out;                      // 64 Mi
    unsigned short* WtT = (unsigned short*)d_out + (size_t)M_TOT * H;  // 4 Mi

    hipMemsetAsync(sums, 0, sums_bytes, stream);

    cvt_f32_bf16<<<dim3((unsigned)(((size_t)M_TOT * H / 8 + 255) / 256)), 256, 0, stream>>>(
        x, xb, (size_t)M_TOT * H);
    transpose_wt<<<dim3(N1 / 64, H / 64), 256, 0, stream>>>(Wt, WtT);
    transpose_wf<<<dim3(H / 64, N1 / 64), 256, 0, stream>>>(Wf, WfT);

    gemm1_mfma<<<dim3(4096), 256, 0, stream>>>(xb, WtT, bt, c1, sums);

    finalize_pq<<<dim3(BATCH * H / 256), 256, 0, stream>>>(sums, ps, Pb, Qb);
    phase_mix<<<dim3(4096), 256, 0, stream>>>(c1, Pb, Qb);

    gemm2_mfma<<<dim3(2048), 256, 0, stream>>>(c1, WfT, bf, out);
}

// Round 4
// 397.037 us; speedup vs baseline: 9.0710x; 1.1043x over previous
//
#include <hip/hip_runtime.h>
#include <hip/hip_bf16.h>
#include <math.h>

#define H 1024
#define N1 2048
#define BATCH 8
#define SEQ 4096
#define M_TOT (BATCH*SEQ)
#define EPS 1e-5f
#define MIX 0.1f

typedef __attribute__((ext_vector_type(8))) short bf16x8;
typedef __attribute__((ext_vector_type(4))) float f32x4;
typedef unsigned int uint_t;

static __device__ __forceinline__ float bf2f(unsigned short u) {
    return __uint_as_float(((unsigned)u) << 16);
}
static __device__ __forceinline__ unsigned short f2bf(float x) {
    __hip_bfloat16 h = __float2bfloat16(x);
    return *reinterpret_cast<unsigned short*>(&h);
}
static __device__ __forceinline__ void gload16(const void* g, void* l) {
    __builtin_amdgcn_global_load_lds(
        (const __attribute__((address_space(1))) unsigned int*)g,
        (__attribute__((address_space(3))) unsigned int*)l,
        16, 0, 0);
}
static __device__ __forceinline__ int perm2h(int c)  { return ((c & 1023) << 1) | (c >> 10); }

// ---------- f32 -> bf16 bulk convert ----------
__global__ __launch_bounds__(256) void cvt_f32_bf16(
    const float* __restrict__ in, unsigned short* __restrict__ out, size_t n)
{
    size_t i = ((size_t)blockIdx.x * 256 + threadIdx.x) * 8;
    if (i >= n) return;
    float4 a = *(const float4*)(in + i);
    float4 b = *(const float4*)(in + i + 4);
    union { unsigned short u[8]; uint4 v; } p;
    p.u[0] = f2bf(a.x); p.u[1] = f2bf(a.y); p.u[2] = f2bf(a.z); p.u[3] = f2bf(a.w);
    p.u[4] = f2bf(b.x); p.u[5] = f2bf(b.y); p.u[6] = f2bf(b.z); p.u[7] = f2bf(b.w);
    *(uint4*)(out + i) = p.v;
}

// ---------- WtT: out[perm2h(c)][r] = Wt[r][c] ----------
__global__ __launch_bounds__(256) void transpose_wt(
    const float* __restrict__ in, unsigned short* __restrict__ out)
{
    __shared__ float tile[64][65];
    const int c0 = blockIdx.x * 64, r0 = blockIdx.y * 64;
    const int tc = threadIdx.x & 63, tr4 = (threadIdx.x >> 6) * 16;
    #pragma unroll
    for (int rr = 0; rr < 16; ++rr)
        tile[tr4 + rr][tc] = in[(size_t)(r0 + tr4 + rr) * N1 + c0 + tc];
    __syncthreads();
    #pragma unroll
    for (int rr = 0; rr < 16; ++rr)
        out[(size_t)perm2h(c0 + tr4 + rr) * H + r0 + tc] = f2bf(tile[tc][tr4 + rr]);
}

// ---------- WfT: out[n][k] = Wf[invperm(k)][n] ----------
__global__ __launch_bounds__(256) void transpose_wf(
    const float* __restrict__ in, unsigned short* __restrict__ out)
{
    __shared__ float tile[64][65];
    const int n0 = blockIdx.x * 64, k0 = blockIdx.y * 64;
    const int tc = threadIdx.x & 63, tr4 = (threadIdx.x >> 6) * 16;
    #pragma unroll
    for (int rr = 0; rr < 16; ++rr) {
        const int k = k0 + tr4 + rr;
        tile[tr4 + rr][tc] = in[(size_t)((k >> 1) | ((k & 1) << 10)) * H + n0 + tc];
    }
    __syncthreads();
    #pragma unroll
    for (int rr = 0; rr < 16; ++rr)
        out[(size_t)(n0 + tr4 + rr) * N1 + k0 + tc] = f2bf(tile[tc][tr4 + rr]);
}

// ================= 256x256 8-phase MFMA GEMM (m201-style template) =================
// 512 thr = 8 waves (2M x 4N); BK=64; LDS 128KB double-buffered; per-phase
// {ds_read subtile | stage 1 half-tile | barrier | lgkmcnt(0) | 16 MFMA | barrier};
// counted vmcnt(4) at phases 4/8 only; 2-bit XOR slot swizzle both sides.
#define VM4 asm volatile("s_waitcnt vmcnt(4)" ::: "memory")
#define VM0 asm volatile("s_waitcnt vmcnt(0)" ::: "memory")

// stage one 16B chunk: operand X (A/B), buffer BB, half HH, chunk CC, k-tile TT
#define STG(X, BB, HH, CC, TT) \
    gload16(X##g + (size_t)((HH)*128 + (CC)*64) * KDIM + (TT)*64, \
            &X##s[BB][(HH)*8192 + (CC)*4096 + t*8])
#define STAGE_HT(X, BB, HH, TT) do { STG(X, BB, HH, 0, TT); STG(X, BB, HH, 1, TT); } while(0)

#define LDA(BB, MF, KS) (*(const bf16x8*)&As[BB][(wr*128 + (MF)*16 + fr)*64 + ((((KS)*4 + lg) ^ rsw))*8])
#define LDB(BB, NF, KS) (*(const bf16x8*)&Bs[BB][(wc*64  + (NF)*16 + fr)*64 + ((((KS)*4 + lg) ^ rsw))*8])

#define PHASE(BB, Q, STAGE_STMT, VM_STMT) do {                                  \
    if ((Q) == 0) {                                                             \
        _Pragma("unroll")                                                       \
        for (int nf = 0; nf < 4; ++nf) {                                        \
            bfr[nf][0] = LDB(BB, nf, 0);                                        \
            bfr[nf][1] = LDB(BB, nf, 1);                                        \
        }                                                                       \
    }                                                                           \
    afr[0][0] = LDA(BB, 2*(Q),   0); afr[0][1] = LDA(BB, 2*(Q),   1);           \
    afr[1][0] = LDA(BB, 2*(Q)+1, 0); afr[1][1] = LDA(BB, 2*(Q)+1, 1);           \
    STAGE_STMT;                                                                 \
    __builtin_amdgcn_s_barrier();                                               \
    asm volatile("s_waitcnt lgkmcnt(0)" ::: "memory");                          \
    __builtin_amdgcn_sched_barrier(0);                                          \
    __builtin_amdgcn_s_setprio(1);                                              \
    _Pragma("unroll")                                                           \
    for (int nf = 0; nf < 4; ++nf) {                                            \
        acc[2*(Q)][nf]   = __builtin_amdgcn_mfma_f32_16x16x32_bf16(afr[0][0], bfr[nf][0], acc[2*(Q)][nf],   0,0,0); \
        acc[2*(Q)][nf]   = __builtin_amdgcn_mfma_f32_16x16x32_bf16(afr[0][1], bfr[nf][1], acc[2*(Q)][nf],   0,0,0); \
        acc[2*(Q)+1][nf] = __builtin_amdgcn_mfma_f32_16x16x32_bf16(afr[1][0], bfr[nf][0], acc[2*(Q)+1][nf], 0,0,0); \
        acc[2*(Q)+1][nf] = __builtin_amdgcn_mfma_f32_16x16x32_bf16(afr[1][1], bfr[nf][1], acc[2*(Q)+1][nf], 0,0,0); \
    }                                                                           \
    __builtin_amdgcn_s_setprio(0);                                              \
    VM_STMT;                                                                    \
    __builtin_amdgcn_s_barrier();                                               \
} while (0)

template<int KDIM, bool G1>
__global__ __launch_bounds__(512, 2) void gemm8(
    const unsigned short* __restrict__ A,
    const unsigned short* __restrict__ Bt,
    const float* __restrict__ bias,
    void* __restrict__ Cout,
    float* __restrict__ sums)
{
    __shared__ __align__(16) unsigned short As[2][16384];
    __shared__ __align__(16) unsigned short Bs[2][16384];

    const int t    = threadIdx.x;
    const int lane = t & 63;
    const int wid  = t >> 6;
    const int wr   = wid >> 2;   // 0..1
    const int wc   = wid & 3;    // 0..3

    int m0, n0;
    if (G1) {   // 1024 blocks: 128/XCD, n-fastest within XCD
        const unsigned wg = ((blockIdx.x & 7) << 7) | (blockIdx.x >> 3);
        n0 = (wg & 7) * 256;
        m0 = (wg >> 3) * 256;
    } else {    // 512 blocks: 64/XCD
        const unsigned wg = ((blockIdx.x & 7) << 6) | (blockIdx.x >> 3);
        n0 = (wg & 3) * 256;
        m0 = (wg >> 2) * 256;
    }

    // staging: thread t covers rows {h*128 + (t>>3), +64}, k-slot (t&7), pre-swizzled source
    const int srow = t >> 3;
    const int ssw  = ((srow >> 1) & 1) | (((srow >> 2) & 1) << 1);
    const int gk   = ((t & 7) ^ ssw) * 8;
    const unsigned short* Ag = A  + (size_t)(m0 + srow) * KDIM + gk;
    const unsigned short* Bg = Bt + (size_t)(n0 + srow) * KDIM + gk;

    // reader: frag row = base + fr; same swizzle bits (bits 1,2 of row come from fr)
    const int fr  = lane & 15;
    const int lg  = lane >> 4;
    const int rsw = ((fr >> 1) & 1) | (((fr >> 2) & 1) << 1);

    f32x4 acc[8][4] = {};
    bf16x8 bfr[4][2];
    bf16x8 afr[2][2];

    constexpr int NITER = KDIM / 128;   // 2 K-tiles (BK=64) per iteration

    // prologue: T0 fully + T1.B halves (steady-state "prev ph7,8"); gate T0
    STAGE_HT(A, 0, 0, 0); STAGE_HT(A, 0, 1, 0);
    STAGE_HT(B, 0, 0, 0); STAGE_HT(B, 0, 1, 0);
    STAGE_HT(B, 1, 0, 1); STAGE_HT(B, 1, 1, 1);
    VM4;
    __builtin_amdgcn_s_barrier();

    for (int it = 0; it < NITER; ++it) {
        const int  T1   = 2 * it + 1;
        const int  T2   = 2 * it + 2;
        const int  T3   = 2 * it + 3;
        const bool more = (it + 1 < NITER);
        // tile T0=2it in buf0 (phases 1-4), T1 in buf1 (phases 5-8)
        PHASE(0, 0, STAGE_HT(A, 1, 0, T1), );                                  // ph1
        PHASE(0, 1, STAGE_HT(A, 1, 1, T1), );                                  // ph2
        PHASE(0, 2, if (more) STAGE_HT(B, 0, 0, T2), );                        // ph3
        PHASE(0, 3, if (more) STAGE_HT(B, 0, 1, T2), if (more) { VM4; } else { VM0; }); // ph4
        PHASE(1, 0, if (more) STAGE_HT(A, 0, 0, T2), );                        // ph5
        PHASE(1, 1, if (more) STAGE_HT(A, 0, 1, T2), );                        // ph6
        PHASE(1, 2, if (more) STAGE_HT(B, 1, 0, T3), );                        // ph7
        PHASE(1, 3, if (more) STAGE_HT(B, 1, 1, T3), if (more) { VM4; });      // ph8
    }

    // ---------------- epilogue ----------------
    const int colbase = n0 + wc * 64;
    if (G1) {
        unsigned short* c1 = (unsigned short*)Cout;
        float lc[4] = {0, 0, 0, 0}, ls[4] = {0, 0, 0, 0};
        #pragma unroll
        for (int nf = 0; nf < 4; ++nf) {
            const int col = colbase + nf * 16 + fr;
            const float bb = bias[(col >> 1) | ((col & 1) << 10)];  // invperm
            #pragma unroll
            for (int mf = 0; mf < 8; ++mf) {
                #pragma unroll
                for (int r = 0; r < 4; ++r) {
                    const float v = acc[mf][nf][r] + bb;
                    const size_t row = (size_t)(m0 + wr * 128 + mf * 16 + lg * 4 + r);
                    c1[row * N1 + col] = f2bf(v);
                    const float oth = __shfl_xor(v, 1);
                    const float re = (fr & 1) ? oth : v;
                    const float im = (fr & 1) ? v : oth;
                    const float rq = rsqrtf(fmaxf(re * re + im * im, 1e-30f));
                    lc[nf] += re * rq;
                    ls[nf] += im * rq;
                }
            }
        }
        #pragma unroll
        for (int nf = 0; nf < 4; ++nf) {
            lc[nf] += __shfl_xor(lc[nf], 16); lc[nf] += __shfl_xor(lc[nf], 32);
            ls[nf] += __shfl_xor(ls[nf], 16); ls[nf] += __shfl_xor(ls[nf], 32);
        }
        if (lane < 16 && !(lane & 1)) {
            const int b = m0 >> 12;
            #pragma unroll
            for (int nf = 0; nf < 4; ++nf) {
                const int hh = (colbase + nf * 16 + fr) >> 1;
                atomicAdd(&sums[(b * 2 + 0) * H + hh], lc[nf]);
                atomicAdd(&sums[(b * 2 + 1) * H + hh], ls[nf]);
            }
        }
    } else {
        float* o = (float*)Cout;
        #pragma unroll
        for (int nf = 0; nf < 4; ++nf) {
            const int col = colbase + nf * 16 + fr;
            const float bb = bias[col];
            #pragma unroll
            for (int mf = 0; mf < 8; ++mf) {
                #pragma unroll
                for (int r = 0; r < 4; ++r) {
                    const size_t row = (size_t)(m0 + wr * 128 + mf * 16 + lg * 4 + r);
                    o[row * H + col] = acc[mf][nf][r] + bb;
                }
            }
        }
    }
}

// ---------- fold phase_shifts + means into P,Q per (b,h) ----------
__global__ void finalize_pq(const float* __restrict__ sums, const float* __restrict__ ps,
                            float* __restrict__ P, float* __restrict__ Q)
{
    int i = blockIdx.x * 256 + threadIdx.x;   // 8192
    int b = i >> 10, h = i & (H - 1);
    float mc = sums[(b * 2 + 0) * H + h] * (1.0f / SEQ);
    float ms = sums[(b * 2 + 1) * H + h] * (1.0f / SEQ);
    float cp = cosf(ps[h]), sp = sinf(ps[h]);
    P[i] = mc * cp + ms * sp;
    Q[i] = ms * cp - mc * sp;
}

// ---------- phase mix, in place, interleaved pairs ----------
__global__ __launch_bounds__(256) void phase_mix(
    unsigned short* __restrict__ c1, const float* __restrict__ P,
    const float* __restrict__ Q)
{
    const size_t total = (size_t)M_TOT * N1 / 8;
    for (size_t q = (size_t)blockIdx.x * 256 + threadIdx.x; q < total;
         q += (size_t)gridDim.x * 256) {
        const size_t m = q >> 8;
        const int off = ((int)q & 255) * 8;
        const int b = (int)(m >> 12);
        const int h0 = off >> 1;
        uint4* cu = (uint4*)c1;
        const size_t idx = ((size_t)m * N1 + off) >> 3;
        uint4 v = cu[idx];
        float4 Pv = *(const float4*)&P[b * H + h0];
        float4 Qv = *(const float4*)&Q[b * H + h0];
        const uint_t w[4] = { v.x, v.y, v.z, v.w };
        const float Pk[4] = { Pv.x, Pv.y, Pv.z, Pv.w };
        const float Qk[4] = { Qv.x, Qv.y, Qv.z, Qv.w };
        uint_t o[4];
        #pragma unroll
        for (int e = 0; e < 4; ++e) {
            float r  = bf2f(w[e] & 0xffff);
            float im = bf2f(w[e] >> 16);
            float tt = r * r + im * im;
            float minv = rsqrtf(fmaxf(tt, 1e-30f));
            float d = MIX * (r * Pk[e] + im * Qk[e]) * minv;
            float d2 = d * d;
            float cd = 1.0f - d2 * (0.5f - d2 * (1.0f / 24.0f));
            float sd = d * (1.0f - d2 * ((1.0f / 6.0f) - d2 * (1.0f / 120.0f)));
            float sc = sqrtf(tt + EPS) * minv;
            o[e] = (uint_t)f2bf(sc * (r * cd - im * sd))
                 | ((uint_t)f2bf(sc * (im * cd + r * sd)) << 16);
        }
        v.x = o[0]; v.y = o[1]; v.z = o[2]; v.w = o[3];
        cu[idx] = v;
    }
}

extern "C" void kernel_launch(void* const* d_in, const int* in_sizes, int n_in,
                              void* d_out, int out_size, void* d_ws, size_t ws_size,
                              hipStream_t stream) {
    const float* x  = (const float*)d_in[0];
    const float* Wt = (const float*)d_in[1];
    const float* bt = (const float*)d_in[2];
    const float* Wf = (const float*)d_in[3];
    const float* bf = (const float*)d_in[4];
    const float* ps = (const float*)d_in[5];
    float* out = (float*)d_out;

    const size_t c1_bytes   = (size_t)M_TOT * N1 * 2;
    const size_t wft_bytes  = (size_t)H * N1 * 2;
    const size_t sums_bytes = (size_t)BATCH * 2 * H * 4;
    const size_t pq_bytes   = (size_t)BATCH * H * 4;
    if (ws_size < c1_bytes + wft_bytes + sums_bytes + 2 * pq_bytes) return;

    unsigned short* c1  = (unsigned short*)d_ws;
    unsigned short* WfT = (unsigned short*)((char*)d_ws + c1_bytes);
    float* sums = (float*)((char*)d_ws + c1_bytes + wft_bytes);
    float* Pb   = (float*)((char*)d_ws + c1_bytes + wft_bytes + sums_bytes);
    float* Qb   = (float*)((char*)d_ws + c1_bytes + wft_bytes + sums_bytes + pq_bytes);

    // d_out doubles as scratch until gemm2 overwrites it
    unsigned short* xb  = (unsigned short*)d_out;                      // 64 Mi
    unsigned short* WtT = (unsigned short*)d_out + (size_t)M_TOT * H;  // 4 Mi

    hipMemsetAsync(sums, 0, sums_bytes, stream);

    cvt_f32_bf16<<<dim3((unsigned)(((size_t)M_TOT * H / 8 + 255) / 256)), 256, 0, stream>>>(
        x, xb, (size_t)M_TOT * H);
    transpose_wt<<<dim3(N1 / 64, H / 64), 256, 0, stream>>>(Wt, WtT);
    transpose_wf<<<dim3(H / 64, N1 / 64), 256, 0, stream>>>(Wf, WfT);

    gemm8<H, true><<<dim3(1024), 512, 0, stream>>>(xb, WtT, bt, (void*)c1, sums);

    finalize_pq<<<dim3(BATCH * H / 256), 256, 0, stream>>>(sums, ps, Pb, Qb);
    phase_mix<<<dim3(4096), 256, 0, stream>>>(c1, Pb, Qb);

    gemm8<N1, false><<<dim3(512), 512, 0, stream>>>(c1, WfT, bf, (void*)out, nullptr);
}

// Round 5
// 366.676 us; speedup vs baseline: 9.8221x; 1.0828x over previous
//
#include <hip/hip_runtime.h>
#include <hip/hip_bf16.h>
#include <math.h>

#define H 1024
#define N1 2048
#define BATCH 8
#define SEQ 4096
#define M_TOT (BATCH*SEQ)
#define EPS 1e-5f
#define MIX 0.1f

typedef __attribute__((ext_vector_type(8))) short bf16x8;
typedef __attribute__((ext_vector_type(4))) float f32x4;
typedef unsigned int uint_t;

static __device__ __forceinline__ float bf2f(unsigned short u) {
    return __uint_as_float(((unsigned)u) << 16);
}
static __device__ __forceinline__ unsigned short f2bf(float x) {
    __hip_bfloat16 h = __float2bfloat16(x);
    return *reinterpret_cast<unsigned short*>(&h);
}
static __device__ __forceinline__ void gload16(const void* g, void* l) {
    __builtin_amdgcn_global_load_lds(
        (const __attribute__((address_space(1))) unsigned int*)g,
        (__attribute__((address_space(3))) unsigned int*)l,
        16, 0, 0);
}
static __device__ __forceinline__ int perm2h(int c)  { return ((c & 1023) << 1) | (c >> 10); }

// ---------- f32 -> bf16 bulk convert ----------
__global__ __launch_bounds__(256) void cvt_f32_bf16(
    const float* __restrict__ in, unsigned short* __restrict__ out, size_t n)
{
    size_t i = ((size_t)blockIdx.x * 256 + threadIdx.x) * 8;
    if (i >= n) return;
    float4 a = *(const float4*)(in + i);
    float4 b = *(const float4*)(in + i + 4);
    union { unsigned short u[8]; uint4 v; } p;
    p.u[0] = f2bf(a.x); p.u[1] = f2bf(a.y); p.u[2] = f2bf(a.z); p.u[3] = f2bf(a.w);
    p.u[4] = f2bf(b.x); p.u[5] = f2bf(b.y); p.u[6] = f2bf(b.z); p.u[7] = f2bf(b.w);
    *(uint4*)(out + i) = p.v;
}

// ---------- WtT: out[perm2h(c)][r] = Wt[r][c] ----------
__global__ __launch_bounds__(256) void transpose_wt(
    const float* __restrict__ in, unsigned short* __restrict__ out)
{
    __shared__ float tile[64][65];
    const int c0 = blockIdx.x * 64, r0 = blockIdx.y * 64;
    const int tc = threadIdx.x & 63, tr4 = (threadIdx.x >> 6) * 16;
    #pragma unroll
    for (int rr = 0; rr < 16; ++rr)
        tile[tr4 + rr][tc] = in[(size_t)(r0 + tr4 + rr) * N1 + c0 + tc];
    __syncthreads();
    #pragma unroll
    for (int rr = 0; rr < 16; ++rr)
        out[(size_t)perm2h(c0 + tr4 + rr) * H + r0 + tc] = f2bf(tile[tc][tr4 + rr]);
}

// ---------- WfT: out[n][k] = Wf[invperm(k)][n] ----------
__global__ __launch_bounds__(256) void transpose_wf(
    const float* __restrict__ in, unsigned short* __restrict__ out)
{
    __shared__ float tile[64][65];
    const int n0 = blockIdx.x * 64, k0 = blockIdx.y * 64;
    const int tc = threadIdx.x & 63, tr4 = (threadIdx.x >> 6) * 16;
    #pragma unroll
    for (int rr = 0; rr < 16; ++rr) {
        const int k = k0 + tr4 + rr;
        tile[tr4 + rr][tc] = in[(size_t)((k >> 1) | ((k & 1) << 10)) * H + n0 + tc];
    }
    __syncthreads();
    #pragma unroll
    for (int rr = 0; rr < 16; ++rr)
        out[(size_t)(n0 + tr4 + rr) * N1 + k0 + tc] = f2bf(tile[tc][tr4 + rr]);
}

// ================= 256x256 8-phase MFMA GEMM =================
// 512 thr = 8 waves (2M x 4N); BK=64; LDS 128KB dbuf; counted vmcnt(4) at ph4/8.
// 3-bit XOR slot swizzle (slot = (ks*4+lg) ^ (row&7)) -> 8 accesses/bank floor.
#define VM4 asm volatile("s_waitcnt vmcnt(4)" ::: "memory")
#define VM0 asm volatile("s_waitcnt vmcnt(0)" ::: "memory")

#define STG(X, BB, HH, CC, TT) \
    gload16(X##g + (size_t)((HH)*128 + (CC)*64) * KDIM + (TT)*64, \
            &X##s[BB][(HH)*8192 + (CC)*4096 + t*8])
#define STAGE_HT(X, BB, HH, TT) do { STG(X, BB, HH, 0, TT); STG(X, BB, HH, 1, TT); } while(0)

#define LDA(BB, MF, KS) (*(const bf16x8*)&As[BB][(wr*128 + (MF)*16 + fr)*64 + ((((KS)*4 + lg) ^ rsw))*8])
#define LDB(BB, NF, KS) (*(const bf16x8*)&Bs[BB][(wc*64  + (NF)*16 + fr)*64 + ((((KS)*4 + lg) ^ rsw))*8])

#define PHASE(BB, Q, STAGE_STMT, VM_STMT) do {                                  \
    if ((Q) == 0) {                                                             \
        _Pragma("unroll")                                                       \
        for (int nf = 0; nf < 4; ++nf) {                                        \
            bfr[nf][0] = LDB(BB, nf, 0);                                        \
            bfr[nf][1] = LDB(BB, nf, 1);                                        \
        }                                                                       \
    }                                                                           \
    afr[0][0] = LDA(BB, 2*(Q),   0); afr[0][1] = LDA(BB, 2*(Q),   1);           \
    afr[1][0] = LDA(BB, 2*(Q)+1, 0); afr[1][1] = LDA(BB, 2*(Q)+1, 1);           \
    STAGE_STMT;                                                                 \
    __builtin_amdgcn_s_barrier();                                               \
    asm volatile("s_waitcnt lgkmcnt(0)" ::: "memory");                          \
    __builtin_amdgcn_sched_barrier(0);                                          \
    __builtin_amdgcn_s_setprio(1);                                              \
    _Pragma("unroll")                                                           \
    for (int nf = 0; nf < 4; ++nf) {                                            \
        acc[2*(Q)][nf]   = __builtin_amdgcn_mfma_f32_16x16x32_bf16(afr[0][0], bfr[nf][0], acc[2*(Q)][nf],   0,0,0); \
        acc[2*(Q)][nf]   = __builtin_amdgcn_mfma_f32_16x16x32_bf16(afr[0][1], bfr[nf][1], acc[2*(Q)][nf],   0,0,0); \
        acc[2*(Q)+1][nf] = __builtin_amdgcn_mfma_f32_16x16x32_bf16(afr[1][0], bfr[nf][0], acc[2*(Q)+1][nf], 0,0,0); \
        acc[2*(Q)+1][nf] = __builtin_amdgcn_mfma_f32_16x16x32_bf16(afr[1][1], bfr[nf][1], acc[2*(Q)+1][nf], 0,0,0); \
    }                                                                           \
    __builtin_amdgcn_s_setprio(0);                                              \
    VM_STMT;                                                                    \
    __builtin_amdgcn_s_barrier();                                               \
} while (0)

template<int KDIM, bool G1>
__global__ __launch_bounds__(512, 2) void gemm8(
    const unsigned short* __restrict__ A,
    const unsigned short* __restrict__ Bt,
    const float* __restrict__ bias,
    void* __restrict__ Cout,
    float* __restrict__ sums)
{
    __shared__ __align__(16) unsigned short As[2][16384];
    __shared__ __align__(16) unsigned short Bs[2][16384];

    const int t    = threadIdx.x;
    const int lane = t & 63;
    const int wid  = t >> 6;
    const int wr   = wid >> 2;   // 0..1
    const int wc   = wid & 3;    // 0..3

    int m0, n0;
    if (G1) {   // 1024 blocks: 128/XCD, n-fastest within XCD
        const unsigned wg = ((blockIdx.x & 7) << 7) | (blockIdx.x >> 3);
        n0 = (wg & 7) * 256;
        m0 = (wg >> 3) * 256;
    } else {    // 512 blocks: 64/XCD
        const unsigned wg = ((blockIdx.x & 7) << 6) | (blockIdx.x >> 3);
        n0 = (wg & 3) * 256;
        m0 = (wg >> 2) * 256;
    }

    // staging: thread t covers rows {h*128 + c*64 + (t>>3)}, k-slot (t&7), 3-bit pre-swizzled src
    const int srow = t >> 3;
    const int ssw  = srow & 7;
    const int gk   = ((t & 7) ^ ssw) * 8;
    const unsigned short* Ag = A  + (size_t)(m0 + srow) * KDIM + gk;
    const unsigned short* Bg = Bt + (size_t)(n0 + srow) * KDIM + gk;

    // reader: row bits 0-2 = fr bits 0-2 -> same swizzle
    const int fr  = lane & 15;
    const int lg  = lane >> 4;
    const int rsw = fr & 7;

    f32x4 acc[8][4] = {};
    bf16x8 bfr[4][2];
    bf16x8 afr[2][2];

    constexpr int NITER = KDIM / 128;   // 2 K-tiles (BK=64) per iteration

    // prologue: T0 fully + T1.B halves
    STAGE_HT(A, 0, 0, 0); STAGE_HT(A, 0, 1, 0);
    STAGE_HT(B, 0, 0, 0); STAGE_HT(B, 0, 1, 0);
    STAGE_HT(B, 1, 0, 1); STAGE_HT(B, 1, 1, 1);
    VM4;
    __builtin_amdgcn_s_barrier();

    for (int it = 0; it < NITER; ++it) {
        const int  T1   = 2 * it + 1;
        const int  T2   = 2 * it + 2;
        const int  T3   = 2 * it + 3;
        const bool more = (it + 1 < NITER);
        PHASE(0, 0, STAGE_HT(A, 1, 0, T1), );                                  // ph1
        PHASE(0, 1, STAGE_HT(A, 1, 1, T1), );                                  // ph2
        PHASE(0, 2, if (more) STAGE_HT(B, 0, 0, T2), );                        // ph3
        PHASE(0, 3, if (more) STAGE_HT(B, 0, 1, T2), if (more) { VM4; } else { VM0; }); // ph4
        PHASE(1, 0, if (more) STAGE_HT(A, 0, 0, T2), );                        // ph5
        PHASE(1, 1, if (more) STAGE_HT(A, 0, 1, T2), );                        // ph6
        PHASE(1, 2, if (more) STAGE_HT(B, 1, 0, T3), );                        // ph7
        PHASE(1, 3, if (more) STAGE_HT(B, 1, 1, T3), if (more) { VM4; });      // ph8
    }

    // ---------------- epilogue ----------------
    const int colbase = n0 + wc * 64;
    if (G1) {
        unsigned short* c1 = (unsigned short*)Cout;
        // bias into acc
        #pragma unroll
        for (int nf = 0; nf < 4; ++nf) {
            const int col = colbase + nf * 16 + fr;
            const float bb = bias[(col >> 1) | ((col & 1) << 10)];  // invperm
            #pragma unroll
            for (int mf = 0; mf < 8; ++mf)
                #pragma unroll
                for (int r = 0; r < 4; ++r)
                    acc[mf][nf][r] += bb;
        }
        // fused stats: cos=r/|z|, sin=i/|z|; pair via lane^1
        float lc[4] = {0, 0, 0, 0}, ls[4] = {0, 0, 0, 0};
        #pragma unroll
        for (int nf = 0; nf < 4; ++nf)
            #pragma unroll
            for (int mf = 0; mf < 8; ++mf)
                #pragma unroll
                for (int r = 0; r < 4; ++r) {
                    const float v = acc[mf][nf][r];
                    const float oth = __shfl_xor(v, 1);
                    const float re = (fr & 1) ? oth : v;
                    const float im = (fr & 1) ? v : oth;
                    const float rq = rsqrtf(fmaxf(re * re + im * im, 1e-30f));
                    lc[nf] += re * rq;
                    ls[nf] += im * rq;
                }
        #pragma unroll
        for (int nf = 0; nf < 4; ++nf) {
            lc[nf] += __shfl_xor(lc[nf], 16); lc[nf] += __shfl_xor(lc[nf], 32);
            ls[nf] += __shfl_xor(ls[nf], 16); ls[nf] += __shfl_xor(ls[nf], 32);
        }
        if (lane < 16 && !(lane & 1)) {
            const int b = m0 >> 12;
            #pragma unroll
            for (int nf = 0; nf < 4; ++nf) {
                const int hh = (colbase + nf * 16 + fr) >> 1;
                atomicAdd(&sums[(b * 2 + 0) * H + hh], lc[nf]);
                atomicAdd(&sums[(b * 2 + 1) * H + hh], ls[nf]);
            }
        }
        // C store via LDS restage (As[0] is dead): pad stride 68 shorts, 16B stores
        unsigned short* cst = &As[0][0] + wid * 2048;
        const int row16 = lane >> 2;
        #pragma unroll
        for (int mf = 0; mf < 8; ++mf) {
            #pragma unroll
            for (int nf = 0; nf < 4; ++nf)
                #pragma unroll
                for (int r = 0; r < 4; ++r)
                    cst[(lg * 4 + r) * 68 + nf * 16 + fr] = f2bf(acc[mf][nf][r]);
            // wave-local: compiler inserts lgkmcnt between write/read
            const size_t grow = (size_t)(m0 + wr * 128 + mf * 16 + row16);
            #pragma unroll
            for (int c = 0; c < 2; ++c) {
                const int chunk = (lane & 3) + c * 4;
                uint4 v = *(const uint4*)&cst[row16 * 68 + chunk * 8];
                *(uint4*)&c1[grow * N1 + colbase + chunk * 8] = v;
            }
        }
    } else {
        float* o = (float*)Cout;
        #pragma unroll
        for (int nf = 0; nf < 4; ++nf) {
            const int col = colbase + nf * 16 + fr;
            const float bb = bias[col];
            #pragma unroll
            for (int mf = 0; mf < 8; ++mf) {
                #pragma unroll
                for (int r = 0; r < 4; ++r) {
                    const size_t row = (size_t)(m0 + wr * 128 + mf * 16 + lg * 4 + r);
                    o[row * H + col] = acc[mf][nf][r] + bb;
                }
            }
        }
    }
}

// ---------- fold phase_shifts + means into P,Q per (b,h) ----------
__global__ void finalize_pq(const float* __restrict__ sums, const float* __restrict__ ps,
                            float* __restrict__ P, float* __restrict__ Q)
{
    int i = blockIdx.x * 256 + threadIdx.x;   // 8192
    int b = i >> 10, h = i & (H - 1);
    float mc = sums[(b * 2 + 0) * H + h] * (1.0f / SEQ);
    float ms = sums[(b * 2 + 1) * H + h] * (1.0f / SEQ);
    float cp = cosf(ps[h]), sp = sinf(ps[h]);
    P[i] = mc * cp + ms * sp;
    Q[i] = ms * cp - mc * sp;
}

// ---------- phase mix, in place, interleaved pairs ----------
__global__ __launch_bounds__(256) void phase_mix(
    unsigned short* __restrict__ c1, const float* __restrict__ P,
    const float* __restrict__ Q)
{
    const size_t total = (size_t)M_TOT * N1 / 8;
    for (size_t q = (size_t)blockIdx.x * 256 + threadIdx.x; q < total;
         q += (size_t)gridDim.x * 256) {
        const size_t m = q >> 8;
        const int off = ((int)q & 255) * 8;
        const int b = (int)(m >> 12);
        const int h0 = off >> 1;
        uint4* cu = (uint4*)c1;
        const size_t idx = ((size_t)m * N1 + off) >> 3;
        uint4 v = cu[idx];
        float4 Pv = *(const float4*)&P[b * H + h0];
        float4 Qv = *(const float4*)&Q[b * H + h0];
        const uint_t w[4] = { v.x, v.y, v.z, v.w };
        const float Pk[4] = { Pv.x, Pv.y, Pv.z, Pv.w };
        const float Qk[4] = { Qv.x, Qv.y, Qv.z, Qv.w };
        uint_t o[4];
        #pragma unroll
        for (int e = 0; e < 4; ++e) {
            float r  = bf2f(w[e] & 0xffff);
            float im = bf2f(w[e] >> 16);
            float tt = r * r + im * im;
            float minv = rsqrtf(fmaxf(tt, 1e-30f));
            float d = MIX * (r * Pk[e] + im * Qk[e]) * minv;
            float d2 = d * d;
            float cd = 1.0f - d2 * (0.5f - d2 * (1.0f / 24.0f));
            float sd = d * (1.0f - d2 * ((1.0f / 6.0f) - d2 * (1.0f / 120.0f)));
            float sc = sqrtf(tt + EPS) * minv;
            o[e] = (uint_t)f2bf(sc * (r * cd - im * sd))
                 | ((uint_t)f2bf(sc * (im * cd + r * sd)) << 16);
        }
        v.x = o[0]; v.y = o[1]; v.z = o[2]; v.w = o[3];
        cu[idx] = v;
    }
}

extern "C" void kernel_launch(void* const* d_in, const int* in_sizes, int n_in,
                              void* d_out, int out_size, void* d_ws, size_t ws_size,
                              hipStream_t stream) {
    const float* x  = (const float*)d_in[0];
    const float* Wt = (const float*)d_in[1];
    const float* bt = (const float*)d_in[2];
    const float* Wf = (const float*)d_in[3];
    const float* bf = (const float*)d_in[4];
    const float* ps = (const float*)d_in[5];
    float* out = (float*)d_out;

    const size_t c1_bytes   = (size_t)M_TOT * N1 * 2;
    const size_t wft_bytes  = (size_t)H * N1 * 2;
    const size_t sums_bytes = (size_t)BATCH * 2 * H * 4;
    const size_t pq_bytes   = (size_t)BATCH * H * 4;
    if (ws_size < c1_bytes + wft_bytes + sums_bytes + 2 * pq_bytes) return;

    unsigned short* c1  = (unsigned short*)d_ws;
    unsigned short* WfT = (unsigned short*)((char*)d_ws + c1_bytes);
    float* sums = (float*)((char*)d_ws + c1_bytes + wft_bytes);
    float* Pb   = (float*)((char*)d_ws + c1_bytes + wft_bytes + sums_bytes);
    float* Qb   = (float*)((char*)d_ws + c1_bytes + wft_bytes + sums_bytes + pq_bytes);

    // d_out doubles as scratch until gemm2 overwrites it
    unsigned short* xb  = (unsigned short*)d_out;                      // 64 Mi
    unsigned short* WtT = (unsigned short*)d_out + (size_t)M_TOT * H;  // 4 Mi

    hipMemsetAsync(sums, 0, sums_bytes, stream);

    cvt_f32_bf16<<<dim3((unsigned)(((size_t)M_TOT * H / 8 + 255) / 256)), 256, 0, stream>>>(
        x, xb, (size_t)M_TOT * H);
    transpose_wt<<<dim3(N1 / 64, H / 64), 256, 0, stream>>>(Wt, WtT);
    transpose_wf<<<dim3(H / 64, N1 / 64), 256, 0, stream>>>(Wf, WfT);

    gemm8<H, true><<<dim3(1024), 512, 0, stream>>>(xb, WtT, bt, (void*)c1, sums);

    finalize_pq<<<dim3(BATCH * H / 256), 256, 0, stream>>>(sums, ps, Pb, Qb);
    phase_mix<<<dim3(4096), 256, 0, stream>>>(c1, Pb, Qb);

    gemm8<N1, false><<<dim3(512), 512, 0, stream>>>(c1, WfT, bf, (void*)out, nullptr);
}